// Round 14
// baseline (977.419 us; speedup 1.0000x reference)
//
#include <hip/hip_runtime.h>
#include <stdint.h>

typedef __bf16 bf16;
typedef __bf16 bf16x8 __attribute__((ext_vector_type(8)));
typedef __bf16 bf16x4 __attribute__((ext_vector_type(4)));
typedef float f32x4 __attribute__((ext_vector_type(4)));

#define DIM   3072
#define SEQ   2048
#define QKVW  9216     // 3*DIM
#define MLPH  12288
#define FUSED 21504    // 3*DIM + MLP_HIDDEN
#define CATW  15360    // DIM + MLP_HIDDEN
#define HD    128
#define NH    24

__device__ __forceinline__ void gload_lds16(const void* g, void* l) {
  __builtin_amdgcn_global_load_lds((__attribute__((address_space(1))) void*)g,
                                   (__attribute__((address_space(3))) void*)l,
                                   16, 0, 0);
}

// gelu-tanh via sigmoid identity: 0.5v(1+tanh(u)) == v * sigmoid(2u)
__device__ __forceinline__ float gelu_fast(float v) {
  float u = 0.7978845608028654f * (v + 0.044715f * v * v * v);
  return v / (1.f + __expf(-2.f * u));
}

// ---------------- K0: mod = silu(temb) @ norm_w.T + norm_b ----------------
__global__ __launch_bounds__(256) void k_mod_gemv(
    const float* __restrict__ temb, const float* __restrict__ nw,
    const float* __restrict__ nb, float* __restrict__ mod)
{
  int j = blockIdx.x * 4 + (threadIdx.x >> 6);
  int lane = threadIdx.x & 63;
  const float* row = nw + (size_t)j * DIM;
  float acc = 0.f;
  #pragma unroll
  for (int k0 = 0; k0 < DIM; k0 += 256) {
    int k = k0 + lane * 4;
    float4 w = *(const float4*)(row + k);
    float4 t = *(const float4*)(temb + k);
    float s0 = t.x / (1.f + __expf(-t.x));
    float s1 = t.y / (1.f + __expf(-t.y));
    float s2 = t.z / (1.f + __expf(-t.z));
    float s3 = t.w / (1.f + __expf(-t.w));
    acc += w.x * s0 + w.y * s1 + w.z * s2 + w.w * s3;
  }
  #pragma unroll
  for (int m = 32; m >= 1; m >>= 1) acc += __shfl_xor(acc, m, 64);
  if (lane == 0) mod[j] = acc + nb[j];
}

// ---------------- K1: LayerNorm + scale/shift -> norm_h (bf16) ----------------
__global__ __launch_bounds__(256) void k_ln_mod(
    const float* __restrict__ hs, const float* __restrict__ mod,
    bf16* __restrict__ nh)
{
  int m = blockIdx.x;
  int t = threadIdx.x;
  const float* x = hs + (size_t)m * DIM;
  float4 v[3];
  float s = 0.f, ss = 0.f;
  #pragma unroll
  for (int i = 0; i < 3; i++) {
    v[i] = *(const float4*)(x + i * 1024 + t * 4);
    s  += v[i].x + v[i].y + v[i].z + v[i].w;
    ss += v[i].x * v[i].x + v[i].y * v[i].y + v[i].z * v[i].z + v[i].w * v[i].w;
  }
  #pragma unroll
  for (int msk = 32; msk >= 1; msk >>= 1) {
    s  += __shfl_xor(s, msk, 64);
    ss += __shfl_xor(ss, msk, 64);
  }
  __shared__ float red[8];
  int wave = t >> 6;
  if ((t & 63) == 0) { red[wave] = s; red[4 + wave] = ss; }
  __syncthreads();
  s  = red[0] + red[1] + red[2] + red[3];
  ss = red[4] + red[5] + red[6] + red[7];
  float mu  = s * (1.f / DIM);
  float var = ss * (1.f / DIM) - mu * mu;
  float rstd = rsqrtf(var + 1e-6f);
  #pragma unroll
  for (int i = 0; i < 3; i++) {
    int col = i * 1024 + t * 4;
    const float* sc = mod + DIM + col;
    const float* sh = mod + col;
    float4 vv = v[i];
    bf16x4 o;
    o[0] = (bf16)((vv.x - mu) * rstd * (1.f + sc[0]) + sh[0]);
    o[1] = (bf16)((vv.y - mu) * rstd * (1.f + sc[1]) + sh[1]);
    o[2] = (bf16)((vv.z - mu) * rstd * (1.f + sc[2]) + sh[2]);
    o[3] = (bf16)((vv.w - mu) * rstd * (1.f + sc[3]) + sh[3]);
    *(bf16x4*)(nh + (size_t)m * DIM + col) = o;
  }
}

// ---------------- K2: f32 -> bf16 weight conversion (both weights, 1 launch) --
__global__ __launch_bounds__(256) void k_cvt2(
    const float* __restrict__ s1, bf16* __restrict__ d1, size_t n1,
    const float* __restrict__ s2, bf16* __restrict__ d2, size_t n2)
{
  int half = gridDim.x >> 1;
  const float* s = (blockIdx.x < half) ? s1 : s2;
  bf16* d        = (blockIdx.x < half) ? d1 : d2;
  size_t n       = (blockIdx.x < half) ? n1 : n2;
  int bid        = (blockIdx.x < half) ? blockIdx.x : blockIdx.x - half;
  size_t stride = (size_t)half * 256 * 8;
  for (size_t i = ((size_t)bid * 256 + threadIdx.x) * 8; i < n; i += stride) {
    float4 a = *(const float4*)(s + i);
    float4 b = *(const float4*)(s + i + 4);
    bf16x8 h;
    h[0] = (bf16)a.x; h[1] = (bf16)a.y; h[2] = (bf16)a.z; h[3] = (bf16)a.w;
    h[4] = (bf16)b.x; h[5] = (bf16)b.y; h[6] = (bf16)b.z; h[7] = (bf16)b.w;
    *(bf16x8*)(d + i) = h;
  }
}

// ================= 256x256 8-wave GEMM, 8-phase schedule (round-11 best) ====
#define MFMA_B16(a, b, c) __builtin_amdgcn_mfma_f32_16x16x32_bf16(a, b, c, 0, 0, 0)

template<int MODE>
__global__ __launch_bounds__(512, 2) void k_gemm8(
    const bf16* __restrict__ A, const bf16* __restrict__ B,
    const float* __restrict__ bias, int K, int ntn, int nkp,
    bf16* __restrict__ oq, bf16* __restrict__ ocat, float* __restrict__ pk)
{
  __shared__ bf16 lds[65536];   // 2 bufs x (A 16384 + B 16384) elems = 128 KiB
  int tid = threadIdx.x;
  int wave = tid >> 6, lane = tid & 63;
  int wm = wave >> 2, wn = wave & 3;

  int nwg = gridDim.x;
  int bid = blockIdx.x;
  int swz = (bid & 7) * (nwg >> 3) + (bid >> 3);
  int mt = swz & 7;
  int rest = swz >> 3;
  int nt = rest % ntn;
  int kc = rest / ntn;
  int m0 = mt * 256, n0 = nt * 256;
  int Kp = K / nkp;
  int kbeg = kc * Kp;
  int NT = Kp >> 6;

  const bf16* Ag = A + (size_t)m0 * K + kbeg;
  const bf16* Bg = B + (size_t)n0 * K + kbeg;

  auto stA = [&](int kt, int q) {
    int kw = kt >= NT ? kt - NT : kt;
    #pragma unroll
    for (int j = 0; j < 2; j++) {
      int c = j * 16 + q * 8 + wave;
      gload_lds16(Ag + (size_t)((c >> 1) * 16 + (lane & 15)) * K
                     + ((c & 1) * 32 + (lane >> 4) * 8) + kw * 64,
                  &lds[((kt & 1) << 15) + c * 512]);
    }
  };
  auto stB = [&](int kt, int q) {
    int kw = kt >= NT ? kt - NT : kt;
    #pragma unroll
    for (int j = 0; j < 2; j++) {
      int v = j * 8 + wave;
      int c = (v >> 2) * 8 + q * 4 + (v & 3);
      gload_lds16(Bg + (size_t)((c >> 1) * 16 + (lane & 15)) * K
                     + ((c & 1) * 32 + (lane >> 4) * 8) + kw * 64,
                  &lds[((kt & 1) << 15) + 16384 + c * 512]);
    }
  };

  f32x4 acc[8][4];
  #pragma unroll
  for (int i = 0; i < 8; i++)
    #pragma unroll
    for (int j = 0; j < 4; j++) acc[i][j] = (f32x4){0.f, 0.f, 0.f, 0.f};

  const int abase = wm * 8192;
  const int bbase = 16384 + wn * 4096;
  const int lo = lane * 8;
  bf16x8 af[8][2], bfr[4][2];

  #define RD_A(MI0, BO) \
    _Pragma("unroll") for (int mi = 0; mi < 4; mi++) \
    _Pragma("unroll") for (int ks = 0; ks < 2; ks++) \
      af[MI0 + mi][ks] = *(const bf16x8*)&lds[(BO) + abase + ((MI0 + mi) * 2 + ks) * 512 + lo];
  #define RD_B(NI0, BO) \
    _Pragma("unroll") for (int ni = 0; ni < 2; ni++) \
    _Pragma("unroll") for (int ks = 0; ks < 2; ks++) \
      bfr[NI0 + ni][ks] = *(const bf16x8*)&lds[(BO) + bbase + ((NI0 + ni) * 2 + ks) * 512 + lo];
  #define QUAD(MI0, NI0) \
    __builtin_amdgcn_s_setprio(1); \
    _Pragma("unroll") for (int ks = 0; ks < 2; ks++) \
    _Pragma("unroll") for (int mi = 0; mi < 4; mi++) \
    _Pragma("unroll") for (int ni = 0; ni < 2; ni++) \
      acc[MI0 + mi][NI0 + ni] = MFMA_B16(af[MI0 + mi][ks], bfr[NI0 + ni][ks], acc[MI0 + mi][NI0 + ni]); \
    __builtin_amdgcn_s_setprio(0);
  #define BAR()   __builtin_amdgcn_s_barrier()
  #define LGKM0() asm volatile("s_waitcnt lgkmcnt(0)" ::: "memory")
  #define LGKM8() asm volatile("s_waitcnt lgkmcnt(8)" ::: "memory")
  #define VM6()   asm volatile("s_waitcnt vmcnt(6)" ::: "memory")
  #define SB0()   __builtin_amdgcn_sched_barrier(0)

  stA(0, 0); stB(0, 0); stA(0, 1); stB(0, 1);
  stA(1, 0); stB(1, 0); stA(1, 1);
  VM6();
  BAR();

  for (int it = 0; it < NT; it += 2) {
    int ta = it, tb = it + 1;
    // ---- P1 ----
    RD_A(0, 0) RD_B(0, 0)
    stB(tb, 1);
    LGKM8();
    BAR(); LGKM0(); SB0();
    QUAD(0, 0)
    BAR();
    // ---- P2 ----
    RD_A(4, 0)
    stA(ta + 2, 0);
    BAR(); LGKM0(); SB0();
    QUAD(4, 0)
    BAR();
    // ---- P3 ----
    RD_B(2, 0)
    stB(ta + 2, 0);
    BAR(); LGKM0(); SB0();
    QUAD(0, 2)
    BAR();
    // ---- P4 ----
    stA(ta + 2, 1);
    VM6();
    BAR(); SB0();
    QUAD(4, 2)
    BAR();
    // ---- P5 ----
    RD_A(0, 32768) RD_B(0, 32768)
    stB(ta + 2, 1);
    LGKM8();
    BAR(); LGKM0(); SB0();
    QUAD(0, 0)
    BAR();
    // ---- P6 ----
    RD_A(4, 32768)
    stA(tb + 2, 0);
    BAR(); LGKM0(); SB0();
    QUAD(4, 0)
    BAR();
    // ---- P7 ----
    RD_B(2, 32768)
    stB(tb + 2, 0);
    BAR(); LGKM0(); SB0();
    QUAD(0, 2)
    BAR();
    // ---- P8 ----
    stA(tb + 2, 1);
    VM6();
    BAR(); SB0();
    QUAD(4, 2)
    BAR();
  }

  int rr = (lane >> 4) * 4, cl = lane & 15;
  int mw0 = m0 + wm * 128, nw0 = n0 + wn * 64;
  #pragma unroll
  for (int mi = 0; mi < 8; mi++) {
    #pragma unroll
    for (int ni = 0; ni < 4; ni++) {
      int n = nw0 + ni * 16 + cl;
      #pragma unroll
      for (int r = 0; r < 4; r++) {
        int m = mw0 + mi * 16 + rr + r;
        float v = acc[mi][ni][r];
        if (MODE == 0) {
          v += bias[n];
          if (n < QKVW) {
            oq[(size_t)m * QKVW + n] = (bf16)v;
          } else {
            ocat[(size_t)m * CATW + DIM + (n - QKVW)] = (bf16)gelu_fast(v);
          }
        } else {
          pk[(size_t)kc * SEQ * DIM + (size_t)m * DIM + n] = v;
        }
      }
    }
  }
  #undef RD_A
  #undef RD_B
  #undef QUAD
  #undef BAR
  #undef LGKM0
  #undef LGKM8
  #undef VM6
  #undef SB0
}

// ---------------- fallback 128x128 GEMM (f32 B), small-ws path ----------------
template<int MODE>
__global__ __launch_bounds__(256) void k_gemm2(
    const bf16* __restrict__ A, const float* __restrict__ Bf,
    const float* __restrict__ bias, int K, int ntn,
    bf16* __restrict__ oq, bf16* __restrict__ ocat,
    const float* __restrict__ gate, const float* __restrict__ resid,
    float* __restrict__ of)
{
  __shared__ bf16 sA[8192];
  __shared__ bf16 sB[8192];
  int nwg = gridDim.x;
  int bid = blockIdx.x;
  int swz = (bid & 7) * (nwg >> 3) + (bid >> 3);
  int mt = swz & 15, nt = swz >> 4;
  int m0 = mt * 128, n0 = nt * 128;
  int tid = threadIdx.x;
  int wave = tid >> 6, lane = tid & 63;
  int wr = wave >> 1, wc = wave & 1;

  size_t aoff[4], boff[4];
  bf16* la[4];
  bf16* lb[4];
  #pragma unroll
  for (int i = 0; i < 4; i++) {
    int c = wave * 4 + i;
    int rt = c >> 1, kt = c & 1;
    int row = rt * 16 + (lane & 15);
    int col = kt * 32 + (lane >> 4) * 8;
    aoff[i] = (size_t)(m0 + row) * K + col;
    boff[i] = (size_t)(n0 + row) * K + col;
    la[i] = sA + c * 512;
    lb[i] = sB + c * 512;
  }
  f32x4 acc[4][4];
  #pragma unroll
  for (int i = 0; i < 4; i++)
    #pragma unroll
    for (int j = 0; j < 4; j++) acc[i][j] = (f32x4){0.f, 0.f, 0.f, 0.f};

  for (int kk = 0; kk < K; kk += 64) {
    #pragma unroll
    for (int i = 0; i < 4; i++)
      gload_lds16(A + aoff[i] + kk, la[i]);
    #pragma unroll
    for (int i = 0; i < 4; i++) {
      const float* g = Bf + boff[i] + kk;
      float4 f0 = *(const float4*)g;
      float4 f1 = *(const float4*)(g + 4);
      bf16x8 h;
      h[0] = (bf16)f0.x; h[1] = (bf16)f0.y; h[2] = (bf16)f0.z; h[3] = (bf16)f0.w;
      h[4] = (bf16)f1.x; h[5] = (bf16)f1.y; h[6] = (bf16)f1.z; h[7] = (bf16)f1.w;
      *(bf16x8*)(lb[i] + lane * 8) = h;
    }
    __syncthreads();
    #pragma unroll
    for (int ks = 0; ks < 2; ks++) {
      bf16x8 af[4], bfr[4];
      #pragma unroll
      for (int mi = 0; mi < 4; mi++)
        af[mi] = *(const bf16x8*)(sA + ((wr * 4 + mi) * 2 + ks) * 512 + lane * 8);
      #pragma unroll
      for (int nj = 0; nj < 4; nj++)
        bfr[nj] = *(const bf16x8*)(sB + ((wc * 4 + nj) * 2 + ks) * 512 + lane * 8);
      #pragma unroll
      for (int mi = 0; mi < 4; mi++)
        #pragma unroll
        for (int nj = 0; nj < 4; nj++)
          acc[mi][nj] = __builtin_amdgcn_mfma_f32_16x16x32_bf16(af[mi], bfr[nj], acc[mi][nj], 0, 0, 0);
    }
    __syncthreads();
  }

  int rr = (lane >> 4) * 4;
  int cl = lane & 15;
  #pragma unroll
  for (int mi = 0; mi < 4; mi++) {
    #pragma unroll
    for (int nj = 0; nj < 4; nj++) {
      int mbase = m0 + wr * 64 + mi * 16 + rr;
      int n = n0 + wc * 64 + nj * 16 + cl;
      #pragma unroll
      for (int r = 0; r < 4; r++) {
        int m = mbase + r;
        float v = acc[mi][nj][r] + bias[n];
        if (MODE == 0) {
          if (n < QKVW) {
            oq[(size_t)m * QKVW + n] = (bf16)v;
          } else {
            ocat[(size_t)m * CATW + DIM + (n - QKVW)] = (bf16)gelu_fast(v);
          }
        } else {
          of[(size_t)m * DIM + n] = gate[n] * v + resid[(size_t)m * DIM + n];
        }
      }
    }
  }
}

// ---------------- split-K reduce: out = gate*(sum pk + bias) + resid ----------------
__global__ __launch_bounds__(256) void k_red(
    const float* __restrict__ pk, const float* __restrict__ bias,
    const float* __restrict__ gate, const float* __restrict__ resid,
    float* __restrict__ out, int parts)
{
  int m = blockIdx.x / 3;
  int n = (blockIdx.x % 3) * 1024 + threadIdx.x * 4;
  size_t idx = (size_t)m * DIM + n;
  f32x4 s = *(const f32x4*)(pk + idx);
  for (int p = 1; p < parts; p++) {
    f32x4 q = *(const f32x4*)(pk + (size_t)p * SEQ * DIM + idx);
    #pragma unroll
    for (int i = 0; i < 4; i++) s[i] += q[i];
  }
  f32x4 b  = *(const f32x4*)(bias + n);
  f32x4 g  = *(const f32x4*)(gate + n);
  f32x4 r  = *(const f32x4*)(resid + idx);
  f32x4 o;
  #pragma unroll
  for (int i = 0; i < 4; i++) o[i] = g[i] * (s[i] + b[i]) + r[i];
  *(f32x4*)(out + idx) = o;
}

// ---------------- K3: per-head RMSNorm + RoPE on q,k (in place, bf16) ----------------
__global__ __launch_bounds__(256) void k_rmsrope(
    bf16* __restrict__ qkv, const float* __restrict__ rc, const float* __restrict__ rs,
    const float* __restrict__ qw, const float* __restrict__ kw)
{
  int srow = blockIdx.x >> 1;
  int isk  = blockIdx.x & 1;
  int off  = isk ? DIM : 0;
  const float* w = isk ? kw : qw;
  int g = threadIdx.x >> 5, gl = threadIdx.x & 31;
  int d = gl * 4;
  #pragma unroll
  for (int hh = 0; hh < 3; hh++) {
    int h = g + hh * 8;
    bf16* p = qkv + (size_t)srow * QKVW + off + h * HD + d;
    bf16x4 u = *(const bf16x4*)p;
    float x0 = (float)u[0], x1 = (float)u[1], x2 = (float)u[2], x3 = (float)u[3];
    float ssq = x0 * x0 + x1 * x1 + x2 * x2 + x3 * x3;
    #pragma unroll
    for (int msk = 16; msk >= 1; msk >>= 1) ssq += __shfl_xor(ssq, msk, 32);
    float r = rsqrtf(ssq * (1.f / HD) + 1e-6f);
    float y0 = x0 * r * w[d], y1 = x1 * r * w[d + 1];
    float y2 = x2 * r * w[d + 2], y3 = x3 * r * w[d + 3];
    const float* c = rc + srow * HD + d;
    const float* sn = rs + srow * HD + d;
    bf16x4 o;
    o[0] = (bf16)(y0 * c[0] - y1 * sn[0]);
    o[1] = (bf16)(y1 * c[1] + y0 * sn[1]);
    o[2] = (bf16)(y2 * c[2] - y3 * sn[2]);
    o[3] = (bf16)(y3 * c[3] + y2 * sn[3]);
    *(bf16x4*)p = o;
  }
}

// ---------------- K4: flash attention -> cat[:, 0:3072] ----------------
// Round-11 kernel + T1 XCD swizzle: 1D grid 768, swz=(bid&7)*96+(bid>>3)
// gives each XCD 96 consecutive work items = 3 whole heads (32 q-tiles each)
// -> per-XCD K/V working set 3 MB (fits 4 MB L2), was ~8x K/V re-fetch.
__global__ __launch_bounds__(256) void k_attn(
    const bf16* __restrict__ qkv, bf16* __restrict__ cat)
{
  int swzb = ((blockIdx.x & 7) * 96) + (blockIdx.x >> 3);   // 768 blocks, %8==0
  int h  = swzb >> 5;
  int q0 = (swzb & 31) * 64;
  int tid = threadIdx.x, wave = tid >> 6, lane = tid & 63;
  int r16 = lane & 15, g4 = lane >> 4;
  __shared__ bf16 sK[32 * 168];
  __shared__ bf16 sVt[128 * 40];
  __shared__ bf16 sP[4][16 * 40];

  bf16x8 qf[4];
  {
    int qrow = q0 + wave * 16 + r16;
    const bf16* qp = qkv + (size_t)qrow * QKVW + h * HD + g4 * 8;
    #pragma unroll
    for (int kc = 0; kc < 4; kc++) qf[kc] = *(const bf16x8*)(qp + kc * 32);
  }
  f32x4 oacc[8];
  #pragma unroll
  for (int dc = 0; dc < 8; dc++) oacc[dc] = (f32x4){0.f, 0.f, 0.f, 0.f};
  float mrow[4] = {-1e30f, -1e30f, -1e30f, -1e30f};
  float lrow[4] = {0.f, 0.f, 0.f, 0.f};
  const float scale = 0.08838834764831845f;

  int krow = tid >> 3, c0 = (tid & 7) * 16;
  const bf16* kbase = qkv + (size_t)krow * QKVW + DIM + h * HD + c0;
  const bf16* vbase = qkv + (size_t)krow * QKVW + 2 * DIM + h * HD + c0;

  bf16x8 kr0 = *(const bf16x8*)(kbase);
  bf16x8 kr1 = *(const bf16x8*)(kbase + 8);
  bf16x8 vr0 = *(const bf16x8*)(vbase);
  bf16x8 vr1 = *(const bf16x8*)(vbase + 8);

  for (int kv0 = 0; kv0 < SEQ; kv0 += 32) {
    *(bf16x8*)&sK[krow * 168 + c0]     = kr0;
    *(bf16x8*)&sK[krow * 168 + c0 + 8] = kr1;
    #pragma unroll
    for (int i = 0; i < 8; i++) {
      sVt[(c0 + i) * 40 + krow]     = vr0[i];
      sVt[(c0 + 8 + i) * 40 + krow] = vr1[i];
    }
    __syncthreads();
    if (kv0 + 32 < SEQ) {
      const bf16* kn = kbase + (size_t)(kv0 + 32) * QKVW;
      const bf16* vn = vbase + (size_t)(kv0 + 32) * QKVW;
      kr0 = *(const bf16x8*)(kn);
      kr1 = *(const bf16x8*)(kn + 8);
      vr0 = *(const bf16x8*)(vn);
      vr1 = *(const bf16x8*)(vn + 8);
    }

    f32x4 sv[2];
    sv[0] = (f32x4){0.f, 0.f, 0.f, 0.f};
    sv[1] = (f32x4){0.f, 0.f, 0.f, 0.f};
    #pragma unroll
    for (int kc = 0; kc < 4; kc++)
      #pragma unroll
      for (int ct = 0; ct < 2; ct++) {
        bf16x8 kf = *(const bf16x8*)&sK[(ct * 16 + r16) * 168 + kc * 32 + g4 * 8];
        sv[ct] = __builtin_amdgcn_mfma_f32_16x16x32_bf16(qf[kc], kf, sv[ct], 0, 0, 0);
      }

    bf16* sPw = &sP[wave][0];
    #pragma unroll
    for (int r = 0; r < 4; r++) {
      float a0 = sv[0][r] * scale, a1 = sv[1][r] * scale;
      float mx = fmaxf(a0, a1);
      #pragma unroll
      for (int msk = 8; msk >= 1; msk >>= 1) mx = fmaxf(mx, __shfl_xor(mx, msk, 16));
      float mnew = fmaxf(mrow[r], mx);
      float so = __expf(mrow[r] - mnew);
      float p0 = __expf(a0 - mnew), p1 = __expf(a1 - mnew);
      float rsum = p0 + p1;
      #pragma unroll
      for (int msk = 8; msk >= 1; msk >>= 1) rsum += __shfl_xor(rsum, msk, 16);
      lrow[r] = lrow[r] * so + rsum;
      mrow[r] = mnew;
      #pragma unroll
      for (int dc = 0; dc < 8; dc++) oacc[dc][r] *= so;
      int prow = g4 * 4 + r;
      sPw[prow * 40 + r16]      = (bf16)p0;
      sPw[prow * 40 + 16 + r16] = (bf16)p1;
    }
    asm volatile("s_waitcnt lgkmcnt(0)" ::: "memory");
    __builtin_amdgcn_sched_barrier(0);
    bf16x8 pa = *(const bf16x8*)&sPw[r16 * 40 + g4 * 8];
    #pragma unroll
    for (int dc = 0; dc < 8; dc++) {
      bf16x8 vf = *(const bf16x8*)&sVt[(dc * 16 + r16) * 40 + g4 * 8];
      oacc[dc] = __builtin_amdgcn_mfma_f32_16x16x32_bf16(pa, vf, oacc[dc], 0, 0, 0);
    }
    __syncthreads();
  }

  #pragma unroll
  for (int dc = 0; dc < 8; dc++) {
    #pragma unroll
    for (int r = 0; r < 4; r++) {
      int qrow = q0 + wave * 16 + g4 * 4 + r;
      int col  = h * HD + dc * 16 + r16;
      cat[(size_t)qrow * CATW + col] = (bf16)(oacc[dc][r] / lrow[r]);
    }
  }
}

// ---------------- launch ----------------
extern "C" void kernel_launch(void* const* d_in, const int* in_sizes, int n_in,
                              void* d_out, int out_size, void* d_ws, size_t ws_size,
                              hipStream_t stream) {
  const float* hs      = (const float*)d_in[0];
  const float* temb    = (const float*)d_in[1];
  const float* rope_c  = (const float*)d_in[2];
  const float* rope_s  = (const float*)d_in[3];
  const float* norm_w  = (const float*)d_in[4];
  const float* norm_b  = (const float*)d_in[5];
  const float* qkvml_w = (const float*)d_in[6];
  const float* qkvml_b = (const float*)d_in[7];
  const float* proj_w  = (const float*)d_in[8];
  const float* proj_b  = (const float*)d_in[9];
  const float* rms_q_w = (const float*)d_in[10];
  const float* rms_k_w = (const float*)d_in[11];
  float* out = (float*)d_out;

  char* ws = (char*)d_ws;
  size_t off = 0;
  float* mod  = (float*)(ws + off); off += 40960;
  bf16*  nh   = (bf16*)(ws + off); off += (size_t)SEQ * DIM * 2;
  bf16*  qkvb = (bf16*)(ws + off); off += (size_t)SEQ * QKVW * 2;
  bf16*  catb = (bf16*)(ws + off); off += (size_t)SEQ * CATW * 2;
  bf16*  wqb  = (bf16*)(ws + off); off += (size_t)FUSED * DIM * 2;
  bf16*  wpb  = (bf16*)(ws + off); off += (size_t)DIM * CATW * 2;
  float* pkbf = (float*)(ws + off);
  size_t base = off;
  int parts = (ws_size >= base + (size_t)2 * SEQ * DIM * 4) ? 2 : 0;
  bool full = (ws_size >= base) && (parts > 0);

  if (full) {
    k_cvt2<<<dim3(4096), dim3(256), 0, stream>>>(
        qkvml_w, wqb, (size_t)FUSED * DIM, proj_w, wpb, (size_t)DIM * CATW);
  }
  k_mod_gemv<<<dim3(QKVW / 4), dim3(256), 0, stream>>>(temb, norm_w, norm_b, mod);
  k_ln_mod<<<dim3(SEQ), dim3(256), 0, stream>>>(hs, mod, nh);

  if (full) {
    k_gemm8<0><<<dim3(8 * (FUSED / 256)), dim3(512), 0, stream>>>(
        nh, wqb, qkvml_b, DIM, FUSED / 256, 1, qkvb, catb, nullptr);
  } else {
    k_gemm2<0><<<dim3(16 * (FUSED / 128)), dim3(256), 0, stream>>>(
        nh, qkvml_w, qkvml_b, DIM, FUSED / 128, qkvb, catb, nullptr, nullptr, nullptr);
  }

  k_rmsrope<<<dim3(SEQ * 2), dim3(256), 0, stream>>>(qkvb, rope_c, rope_s, rms_q_w, rms_k_w);
  k_attn<<<dim3(SEQ / 64 * NH), dim3(256), 0, stream>>>(qkvb, catb);

  if (full) {
    k_gemm8<1><<<dim3(8 * (DIM / 256) * parts), dim3(512), 0, stream>>>(
        catb, wpb, nullptr, CATW, DIM / 256, parts, nullptr, nullptr, pkbf);
    k_red<<<dim3(SEQ * 3), dim3(256), 0, stream>>>(pkbf, proj_b, mod + 2 * DIM, hs, out, parts);
  } else {
    k_gemm2<1><<<dim3(16 * (DIM / 128)), dim3(256), 0, stream>>>(
        catb, proj_w, proj_b, CATW, DIM / 128, nullptr, nullptr, mod + 2 * DIM, hs, out);
  }
}

// Round 15
// 952.506 us; speedup vs baseline: 1.0262x; 1.0262x over previous
//
#include <hip/hip_runtime.h>
#include <stdint.h>

typedef __bf16 bf16;
typedef __bf16 bf16x8 __attribute__((ext_vector_type(8)));
typedef __bf16 bf16x4 __attribute__((ext_vector_type(4)));
typedef float f32x4 __attribute__((ext_vector_type(4)));

#define DIM   3072
#define SEQ   2048
#define QKVW  9216     // 3*DIM
#define MLPH  12288
#define FUSED 21504    // 3*DIM + MLP_HIDDEN
#define CATW  15360    // DIM + MLP_HIDDEN
#define HD    128
#define NH    24

__device__ __forceinline__ void gload_lds16(const void* g, void* l) {
  __builtin_amdgcn_global_load_lds((__attribute__((address_space(1))) void*)g,
                                   (__attribute__((address_space(3))) void*)l,
                                   16, 0, 0);
}

// gelu-tanh via sigmoid identity: 0.5v(1+tanh(u)) == v * sigmoid(2u)
__device__ __forceinline__ float gelu_fast(float v) {
  float u = 0.7978845608028654f * (v + 0.044715f * v * v * v);
  return v / (1.f + __expf(-2.f * u));
}

// ---------------- K0: mod = silu(temb) @ norm_w.T + norm_b ----------------
__global__ __launch_bounds__(256) void k_mod_gemv(
    const float* __restrict__ temb, const float* __restrict__ nw,
    const float* __restrict__ nb, float* __restrict__ mod)
{
  int j = blockIdx.x * 4 + (threadIdx.x >> 6);
  int lane = threadIdx.x & 63;
  const float* row = nw + (size_t)j * DIM;
  float acc = 0.f;
  #pragma unroll
  for (int k0 = 0; k0 < DIM; k0 += 256) {
    int k = k0 + lane * 4;
    float4 w = *(const float4*)(row + k);
    float4 t = *(const float4*)(temb + k);
    float s0 = t.x / (1.f + __expf(-t.x));
    float s1 = t.y / (1.f + __expf(-t.y));
    float s2 = t.z / (1.f + __expf(-t.z));
    float s3 = t.w / (1.f + __expf(-t.w));
    acc += w.x * s0 + w.y * s1 + w.z * s2 + w.w * s3;
  }
  #pragma unroll
  for (int m = 32; m >= 1; m >>= 1) acc += __shfl_xor(acc, m, 64);
  if (lane == 0) mod[j] = acc + nb[j];
}

// ---------------- K1: LayerNorm + scale/shift -> norm_h (bf16) ----------------
__global__ __launch_bounds__(256) void k_ln_mod(
    const float* __restrict__ hs, const float* __restrict__ mod,
    bf16* __restrict__ nh)
{
  int m = blockIdx.x;
  int t = threadIdx.x;
  const float* x = hs + (size_t)m * DIM;
  float4 v[3];
  float s = 0.f, ss = 0.f;
  #pragma unroll
  for (int i = 0; i < 3; i++) {
    v[i] = *(const float4*)(x + i * 1024 + t * 4);
    s  += v[i].x + v[i].y + v[i].z + v[i].w;
    ss += v[i].x * v[i].x + v[i].y * v[i].y + v[i].z * v[i].z + v[i].w * v[i].w;
  }
  #pragma unroll
  for (int msk = 32; msk >= 1; msk >>= 1) {
    s  += __shfl_xor(s, msk, 64);
    ss += __shfl_xor(ss, msk, 64);
  }
  __shared__ float red[8];
  int wave = t >> 6;
  if ((t & 63) == 0) { red[wave] = s; red[4 + wave] = ss; }
  __syncthreads();
  s  = red[0] + red[1] + red[2] + red[3];
  ss = red[4] + red[5] + red[6] + red[7];
  float mu  = s * (1.f / DIM);
  float var = ss * (1.f / DIM) - mu * mu;
  float rstd = rsqrtf(var + 1e-6f);
  #pragma unroll
  for (int i = 0; i < 3; i++) {
    int col = i * 1024 + t * 4;
    const float* sc = mod + DIM + col;
    const float* sh = mod + col;
    float4 vv = v[i];
    bf16x4 o;
    o[0] = (bf16)((vv.x - mu) * rstd * (1.f + sc[0]) + sh[0]);
    o[1] = (bf16)((vv.y - mu) * rstd * (1.f + sc[1]) + sh[1]);
    o[2] = (bf16)((vv.z - mu) * rstd * (1.f + sc[2]) + sh[2]);
    o[3] = (bf16)((vv.w - mu) * rstd * (1.f + sc[3]) + sh[3]);
    *(bf16x4*)(nh + (size_t)m * DIM + col) = o;
  }
}

// ---------------- K2: f32 -> bf16 weight conversion (both weights, 1 launch) --
__global__ __launch_bounds__(256) void k_cvt2(
    const float* __restrict__ s1, bf16* __restrict__ d1, size_t n1,
    const float* __restrict__ s2, bf16* __restrict__ d2, size_t n2)
{
  int half = gridDim.x >> 1;
  const float* s = (blockIdx.x < half) ? s1 : s2;
  bf16* d        = (blockIdx.x < half) ? d1 : d2;
  size_t n       = (blockIdx.x < half) ? n1 : n2;
  int bid        = (blockIdx.x < half) ? blockIdx.x : blockIdx.x - half;
  size_t stride = (size_t)half * 256 * 8;
  for (size_t i = ((size_t)bid * 256 + threadIdx.x) * 8; i < n; i += stride) {
    float4 a = *(const float4*)(s + i);
    float4 b = *(const float4*)(s + i + 4);
    bf16x8 h;
    h[0] = (bf16)a.x; h[1] = (bf16)a.y; h[2] = (bf16)a.z; h[3] = (bf16)a.w;
    h[4] = (bf16)b.x; h[5] = (bf16)b.y; h[6] = (bf16)b.z; h[7] = (bf16)b.w;
    *(bf16x8*)(d + i) = h;
  }
}

// ================= 256x256 8-wave GEMM, 8-phase schedule ====================
// MODE 0: n<9216 -> qkv bf16 ; n>=9216 -> gelu -> cat[:,3072+...] bf16
// MODE 1: bf16 partials to pk[kc] (split-K, reduced in f32 by k_red)
#define MFMA_B16(a, b, c) __builtin_amdgcn_mfma_f32_16x16x32_bf16(a, b, c, 0, 0, 0)

template<int MODE>
__global__ __launch_bounds__(512, 2) void k_gemm8(
    const bf16* __restrict__ A, const bf16* __restrict__ B,
    const float* __restrict__ bias, int K, int ntn, int nkp,
    bf16* __restrict__ oq, bf16* __restrict__ ocat, bf16* __restrict__ pk)
{
  __shared__ bf16 lds[65536];   // 2 bufs x (A 16384 + B 16384) elems = 128 KiB
  int tid = threadIdx.x;
  int wave = tid >> 6, lane = tid & 63;
  int wm = wave >> 2, wn = wave & 3;

  int nwg = gridDim.x;
  int bid = blockIdx.x;
  int swz = (bid & 7) * (nwg >> 3) + (bid >> 3);
  int mt = swz & 7;
  int rest = swz >> 3;
  int nt = rest % ntn;
  int kc = rest / ntn;
  int m0 = mt * 256, n0 = nt * 256;
  int Kp = K / nkp;
  int kbeg = kc * Kp;
  int NT = Kp >> 6;

  const bf16* Ag = A + (size_t)m0 * K + kbeg;
  const bf16* Bg = B + (size_t)n0 * K + kbeg;

  auto stA = [&](int kt, int q) {
    int kw = kt >= NT ? kt - NT : kt;
    #pragma unroll
    for (int j = 0; j < 2; j++) {
      int c = j * 16 + q * 8 + wave;
      gload_lds16(Ag + (size_t)((c >> 1) * 16 + (lane & 15)) * K
                     + ((c & 1) * 32 + (lane >> 4) * 8) + kw * 64,
                  &lds[((kt & 1) << 15) + c * 512]);
    }
  };
  auto stB = [&](int kt, int q) {
    int kw = kt >= NT ? kt - NT : kt;
    #pragma unroll
    for (int j = 0; j < 2; j++) {
      int v = j * 8 + wave;
      int c = (v >> 2) * 8 + q * 4 + (v & 3);
      gload_lds16(Bg + (size_t)((c >> 1) * 16 + (lane & 15)) * K
                     + ((c & 1) * 32 + (lane >> 4) * 8) + kw * 64,
                  &lds[((kt & 1) << 15) + 16384 + c * 512]);
    }
  };

  f32x4 acc[8][4];
  #pragma unroll
  for (int i = 0; i < 8; i++)
    #pragma unroll
    for (int j = 0; j < 4; j++) acc[i][j] = (f32x4){0.f, 0.f, 0.f, 0.f};

  const int abase = wm * 8192;
  const int bbase = 16384 + wn * 4096;
  const int lo = lane * 8;
  bf16x8 af[8][2], bfr[4][2];

  #define RD_A(MI0, BO) \
    _Pragma("unroll") for (int mi = 0; mi < 4; mi++) \
    _Pragma("unroll") for (int ks = 0; ks < 2; ks++) \
      af[MI0 + mi][ks] = *(const bf16x8*)&lds[(BO) + abase + ((MI0 + mi) * 2 + ks) * 512 + lo];
  #define RD_B(NI0, BO) \
    _Pragma("unroll") for (int ni = 0; ni < 2; ni++) \
    _Pragma("unroll") for (int ks = 0; ks < 2; ks++) \
      bfr[NI0 + ni][ks] = *(const bf16x8*)&lds[(BO) + bbase + ((NI0 + ni) * 2 + ks) * 512 + lo];
  #define QUAD(MI0, NI0) \
    __builtin_amdgcn_s_setprio(1); \
    _Pragma("unroll") for (int ks = 0; ks < 2; ks++) \
    _Pragma("unroll") for (int mi = 0; mi < 4; mi++) \
    _Pragma("unroll") for (int ni = 0; ni < 2; ni++) \
      acc[MI0 + mi][NI0 + ni] = MFMA_B16(af[MI0 + mi][ks], bfr[NI0 + ni][ks], acc[MI0 + mi][NI0 + ni]); \
    __builtin_amdgcn_s_setprio(0);
  #define BAR()   __builtin_amdgcn_s_barrier()
  #define LGKM0() asm volatile("s_waitcnt lgkmcnt(0)" ::: "memory")
  #define LGKM8() asm volatile("s_waitcnt lgkmcnt(8)" ::: "memory")
  #define VM6()   asm volatile("s_waitcnt vmcnt(6)" ::: "memory")
  #define SB0()   __builtin_amdgcn_sched_barrier(0)

  stA(0, 0); stB(0, 0); stA(0, 1); stB(0, 1);
  stA(1, 0); stB(1, 0); stA(1, 1);
  VM6();
  BAR();

  for (int it = 0; it < NT; it += 2) {
    int ta = it, tb = it + 1;
    // ---- P1 ----
    RD_A(0, 0) RD_B(0, 0)
    stB(tb, 1);
    LGKM8();
    BAR(); LGKM0(); SB0();
    QUAD(0, 0)
    BAR();
    // ---- P2 ----
    RD_A(4, 0)
    stA(ta + 2, 0);
    BAR(); LGKM0(); SB0();
    QUAD(4, 0)
    BAR();
    // ---- P3 ----
    RD_B(2, 0)
    stB(ta + 2, 0);
    BAR(); LGKM0(); SB0();
    QUAD(0, 2)
    BAR();
    // ---- P4 ----
    stA(ta + 2, 1);
    VM6();
    BAR(); SB0();
    QUAD(4, 2)
    BAR();
    // ---- P5 ----
    RD_A(0, 32768) RD_B(0, 32768)
    stB(ta + 2, 1);
    LGKM8();
    BAR(); LGKM0(); SB0();
    QUAD(0, 0)
    BAR();
    // ---- P6 ----
    RD_A(4, 32768)
    stA(tb + 2, 0);
    BAR(); LGKM0(); SB0();
    QUAD(4, 0)
    BAR();
    // ---- P7 ----
    RD_B(2, 32768)
    stB(tb + 2, 0);
    BAR(); LGKM0(); SB0();
    QUAD(0, 2)
    BAR();
    // ---- P8 ----
    stA(tb + 2, 1);
    VM6();
    BAR(); SB0();
    QUAD(4, 2)
    BAR();
  }

  int rr = (lane >> 4) * 4, cl = lane & 15;
  int mw0 = m0 + wm * 128, nw0 = n0 + wn * 64;
  #pragma unroll
  for (int mi = 0; mi < 8; mi++) {
    #pragma unroll
    for (int ni = 0; ni < 4; ni++) {
      int n = nw0 + ni * 16 + cl;
      #pragma unroll
      for (int r = 0; r < 4; r++) {
        int m = mw0 + mi * 16 + rr + r;
        float v = acc[mi][ni][r];
        if (MODE == 0) {
          v += bias[n];
          if (n < QKVW) {
            oq[(size_t)m * QKVW + n] = (bf16)v;
          } else {
            ocat[(size_t)m * CATW + DIM + (n - QKVW)] = (bf16)gelu_fast(v);
          }
        } else {
          pk[(size_t)kc * SEQ * DIM + (size_t)m * DIM + n] = (bf16)v;
        }
      }
    }
  }
  #undef RD_A
  #undef RD_B
  #undef QUAD
  #undef BAR
  #undef LGKM0
  #undef LGKM8
  #undef VM6
  #undef SB0
}

// ---------------- fallback 128x128 GEMM (f32 B), small-ws path ----------------
template<int MODE>
__global__ __launch_bounds__(256) void k_gemm2(
    const bf16* __restrict__ A, const float* __restrict__ Bf,
    const float* __restrict__ bias, int K, int ntn,
    bf16* __restrict__ oq, bf16* __restrict__ ocat,
    const float* __restrict__ gate, const float* __restrict__ resid,
    float* __restrict__ of)
{
  __shared__ bf16 sA[8192];
  __shared__ bf16 sB[8192];
  int nwg = gridDim.x;
  int bid = blockIdx.x;
  int swz = (bid & 7) * (nwg >> 3) + (bid >> 3);
  int mt = swz & 15, nt = swz >> 4;
  int m0 = mt * 128, n0 = nt * 128;
  int tid = threadIdx.x;
  int wave = tid >> 6, lane = tid & 63;
  int wr = wave >> 1, wc = wave & 1;

  size_t aoff[4], boff[4];
  bf16* la[4];
  bf16* lb[4];
  #pragma unroll
  for (int i = 0; i < 4; i++) {
    int c = wave * 4 + i;
    int rt = c >> 1, kt = c & 1;
    int row = rt * 16 + (lane & 15);
    int col = kt * 32 + (lane >> 4) * 8;
    aoff[i] = (size_t)(m0 + row) * K + col;
    boff[i] = (size_t)(n0 + row) * K + col;
    la[i] = sA + c * 512;
    lb[i] = sB + c * 512;
  }
  f32x4 acc[4][4];
  #pragma unroll
  for (int i = 0; i < 4; i++)
    #pragma unroll
    for (int j = 0; j < 4; j++) acc[i][j] = (f32x4){0.f, 0.f, 0.f, 0.f};

  for (int kk = 0; kk < K; kk += 64) {
    #pragma unroll
    for (int i = 0; i < 4; i++)
      gload_lds16(A + aoff[i] + kk, la[i]);
    #pragma unroll
    for (int i = 0; i < 4; i++) {
      const float* g = Bf + boff[i] + kk;
      float4 f0 = *(const float4*)g;
      float4 f1 = *(const float4*)(g + 4);
      bf16x8 h;
      h[0] = (bf16)f0.x; h[1] = (bf16)f0.y; h[2] = (bf16)f0.z; h[3] = (bf16)f0.w;
      h[4] = (bf16)f1.x; h[5] = (bf16)f1.y; h[6] = (bf16)f1.z; h[7] = (bf16)f1.w;
      *(bf16x8*)(lb[i] + lane * 8) = h;
    }
    __syncthreads();
    #pragma unroll
    for (int ks = 0; ks < 2; ks++) {
      bf16x8 af[4], bfr[4];
      #pragma unroll
      for (int mi = 0; mi < 4; mi++)
        af[mi] = *(const bf16x8*)(sA + ((wr * 4 + mi) * 2 + ks) * 512 + lane * 8);
      #pragma unroll
      for (int nj = 0; nj < 4; nj++)
        bfr[nj] = *(const bf16x8*)(sB + ((wc * 4 + nj) * 2 + ks) * 512 + lane * 8);
      #pragma unroll
      for (int mi = 0; mi < 4; mi++)
        #pragma unroll
        for (int nj = 0; nj < 4; nj++)
          acc[mi][nj] = __builtin_amdgcn_mfma_f32_16x16x32_bf16(af[mi], bfr[nj], acc[mi][nj], 0, 0, 0);
    }
    __syncthreads();
  }

  int rr = (lane >> 4) * 4;
  int cl = lane & 15;
  #pragma unroll
  for (int mi = 0; mi < 4; mi++) {
    #pragma unroll
    for (int nj = 0; nj < 4; nj++) {
      int mbase = m0 + wr * 64 + mi * 16 + rr;
      int n = n0 + wc * 64 + nj * 16 + cl;
      #pragma unroll
      for (int r = 0; r < 4; r++) {
        int m = mbase + r;
        float v = acc[mi][nj][r] + bias[n];
        if (MODE == 0) {
          if (n < QKVW) {
            oq[(size_t)m * QKVW + n] = (bf16)v;
          } else {
            ocat[(size_t)m * CATW + DIM + (n - QKVW)] = (bf16)gelu_fast(v);
          }
        } else {
          of[(size_t)m * DIM + n] = gate[n] * v + resid[(size_t)m * DIM + n];
        }
      }
    }
  }
}

// ---------------- split-K reduce: out = gate*(sum bf16 pk + bias) + resid ----
__global__ __launch_bounds__(256) void k_red(
    const bf16* __restrict__ pk, const float* __restrict__ bias,
    const float* __restrict__ gate, const float* __restrict__ resid,
    float* __restrict__ out, int parts)
{
  int m = blockIdx.x / 3;
  int n = (blockIdx.x % 3) * 1024 + threadIdx.x * 4;
  size_t idx = (size_t)m * DIM + n;
  f32x4 s = (f32x4){0.f, 0.f, 0.f, 0.f};
  for (int p = 0; p < parts; p++) {
    bf16x4 q = *(const bf16x4*)(pk + (size_t)p * SEQ * DIM + idx);
    #pragma unroll
    for (int i = 0; i < 4; i++) s[i] += (float)q[i];
  }
  f32x4 b  = *(const f32x4*)(bias + n);
  f32x4 g  = *(const f32x4*)(gate + n);
  f32x4 r  = *(const f32x4*)(resid + idx);
  f32x4 o;
  #pragma unroll
  for (int i = 0; i < 4; i++) o[i] = g[i] * (s[i] + b[i]) + r[i];
  *(f32x4*)(out + idx) = o;
}

// ---------------- K3: per-head RMSNorm + RoPE on q,k (in place, bf16) ----------------
__global__ __launch_bounds__(256) void k_rmsrope(
    bf16* __restrict__ qkv, const float* __restrict__ rc, const float* __restrict__ rs,
    const float* __restrict__ qw, const float* __restrict__ kw)
{
  int srow = blockIdx.x >> 1;
  int isk  = blockIdx.x & 1;
  int off  = isk ? DIM : 0;
  const float* w = isk ? kw : qw;
  int g = threadIdx.x >> 5, gl = threadIdx.x & 31;
  int d = gl * 4;
  #pragma unroll
  for (int hh = 0; hh < 3; hh++) {
    int h = g + hh * 8;
    bf16* p = qkv + (size_t)srow * QKVW + off + h * HD + d;
    bf16x4 u = *(const bf16x4*)p;
    float x0 = (float)u[0], x1 = (float)u[1], x2 = (float)u[2], x3 = (float)u[3];
    float ssq = x0 * x0 + x1 * x1 + x2 * x2 + x3 * x3;
    #pragma unroll
    for (int msk = 16; msk >= 1; msk >>= 1) ssq += __shfl_xor(ssq, msk, 32);
    float r = rsqrtf(ssq * (1.f / HD) + 1e-6f);
    float y0 = x0 * r * w[d], y1 = x1 * r * w[d + 1];
    float y2 = x2 * r * w[d + 2], y3 = x3 * r * w[d + 3];
    const float* c = rc + srow * HD + d;
    const float* sn = rs + srow * HD + d;
    bf16x4 o;
    o[0] = (bf16)(y0 * c[0] - y1 * sn[0]);
    o[1] = (bf16)(y1 * c[1] + y0 * sn[1]);
    o[2] = (bf16)(y2 * c[2] - y3 * sn[2]);
    o[3] = (bf16)(y3 * c[3] + y2 * sn[3]);
    *(bf16x4*)p = o;
  }
}

// ---------------- K4: flash attention -> cat[:, 0:3072] ----------------
__global__ __launch_bounds__(256) void k_attn(
    const bf16* __restrict__ qkv, bf16* __restrict__ cat)
{
  int swzb = ((blockIdx.x & 7) * 96) + (blockIdx.x >> 3);   // 768 blocks, %8==0
  int h  = swzb >> 5;
  int q0 = (swzb & 31) * 64;
  int tid = threadIdx.x, wave = tid >> 6, lane = tid & 63;
  int r16 = lane & 15, g4 = lane >> 4;
  __shared__ bf16 sK[32 * 168];
  __shared__ bf16 sVt[128 * 40];
  __shared__ bf16 sP[4][16 * 40];

  bf16x8 qf[4];
  {
    int qrow = q0 + wave * 16 + r16;
    const bf16* qp = qkv + (size_t)qrow * QKVW + h * HD + g4 * 8;
    #pragma unroll
    for (int kc = 0; kc < 4; kc++) qf[kc] = *(const bf16x8*)(qp + kc * 32);
  }
  f32x4 oacc[8];
  #pragma unroll
  for (int dc = 0; dc < 8; dc++) oacc[dc] = (f32x4){0.f, 0.f, 0.f, 0.f};
  float mrow[4] = {-1e30f, -1e30f, -1e30f, -1e30f};
  float lrow[4] = {0.f, 0.f, 0.f, 0.f};
  const float scale = 0.08838834764831845f;

  int krow = tid >> 3, c0 = (tid & 7) * 16;
  const bf16* kbase = qkv + (size_t)krow * QKVW + DIM + h * HD + c0;
  const bf16* vbase = qkv + (size_t)krow * QKVW + 2 * DIM + h * HD + c0;

  bf16x8 kr0 = *(const bf16x8*)(kbase);
  bf16x8 kr1 = *(const bf16x8*)(kbase + 8);
  bf16x8 vr0 = *(const bf16x8*)(vbase);
  bf16x8 vr1 = *(const bf16x8*)(vbase + 8);

  for (int kv0 = 0; kv0 < SEQ; kv0 += 32) {
    *(bf16x8*)&sK[krow * 168 + c0]     = kr0;
    *(bf16x8*)&sK[krow * 168 + c0 + 8] = kr1;
    #pragma unroll
    for (int i = 0; i < 8; i++) {
      sVt[(c0 + i) * 40 + krow]     = vr0[i];
      sVt[(c0 + 8 + i) * 40 + krow] = vr1[i];
    }
    __syncthreads();
    if (kv0 + 32 < SEQ) {
      const bf16* kn = kbase + (size_t)(kv0 + 32) * QKVW;
      const bf16* vn = vbase + (size_t)(kv0 + 32) * QKVW;
      kr0 = *(const bf16x8*)(kn);
      kr1 = *(const bf16x8*)(kn + 8);
      vr0 = *(const bf16x8*)(vn);
      vr1 = *(const bf16x8*)(vn + 8);
    }

    f32x4 sv[2];
    sv[0] = (f32x4){0.f, 0.f, 0.f, 0.f};
    sv[1] = (f32x4){0.f, 0.f, 0.f, 0.f};
    #pragma unroll
    for (int kc = 0; kc < 4; kc++)
      #pragma unroll
      for (int ct = 0; ct < 2; ct++) {
        bf16x8 kf = *(const bf16x8*)&sK[(ct * 16 + r16) * 168 + kc * 32 + g4 * 8];
        sv[ct] = __builtin_amdgcn_mfma_f32_16x16x32_bf16(qf[kc], kf, sv[ct], 0, 0, 0);
      }

    bf16* sPw = &sP[wave][0];
    #pragma unroll
    for (int r = 0; r < 4; r++) {
      float a0 = sv[0][r] * scale, a1 = sv[1][r] * scale;
      float mx = fmaxf(a0, a1);
      #pragma unroll
      for (int msk = 8; msk >= 1; msk >>= 1) mx = fmaxf(mx, __shfl_xor(mx, msk, 16));
      float mnew = fmaxf(mrow[r], mx);
      float so = __expf(mrow[r] - mnew);
      float p0 = __expf(a0 - mnew), p1 = __expf(a1 - mnew);
      float rsum = p0 + p1;
      #pragma unroll
      for (int msk = 8; msk >= 1; msk >>= 1) rsum += __shfl_xor(rsum, msk, 16);
      lrow[r] = lrow[r] * so + rsum;
      mrow[r] = mnew;
      #pragma unroll
      for (int dc = 0; dc < 8; dc++) oacc[dc][r] *= so;
      int prow = g4 * 4 + r;
      sPw[prow * 40 + r16]      = (bf16)p0;
      sPw[prow * 40 + 16 + r16] = (bf16)p1;
    }
    asm volatile("s_waitcnt lgkmcnt(0)" ::: "memory");
    __builtin_amdgcn_sched_barrier(0);
    bf16x8 pa = *(const bf16x8*)&sPw[r16 * 40 + g4 * 8];
    #pragma unroll
    for (int dc = 0; dc < 8; dc++) {
      bf16x8 vf = *(const bf16x8*)&sVt[(dc * 16 + r16) * 40 + g4 * 8];
      oacc[dc] = __builtin_amdgcn_mfma_f32_16x16x32_bf16(pa, vf, oacc[dc], 0, 0, 0);
    }
    __syncthreads();
  }

  #pragma unroll
  for (int dc = 0; dc < 8; dc++) {
    #pragma unroll
    for (int r = 0; r < 4; r++) {
      int qrow = q0 + wave * 16 + g4 * 4 + r;
      int col  = h * HD + dc * 16 + r16;
      cat[(size_t)qrow * CATW + col] = (bf16)(oacc[dc][r] / lrow[r]);
    }
  }
}

// ---------------- launch ----------------
extern "C" void kernel_launch(void* const* d_in, const int* in_sizes, int n_in,
                              void* d_out, int out_size, void* d_ws, size_t ws_size,
                              hipStream_t stream) {
  const float* hs      = (const float*)d_in[0];
  const float* temb    = (const float*)d_in[1];
  const float* rope_c  = (const float*)d_in[2];
  const float* rope_s  = (const float*)d_in[3];
  const float* norm_w  = (const float*)d_in[4];
  const float* norm_b  = (const float*)d_in[5];
  const float* qkvml_w = (const float*)d_in[6];
  const float* qkvml_b = (const float*)d_in[7];
  const float* proj_w  = (const float*)d_in[8];
  const float* proj_b  = (const float*)d_in[9];
  const float* rms_q_w = (const float*)d_in[10];
  const float* rms_k_w = (const float*)d_in[11];
  float* out = (float*)d_out;

  char* ws = (char*)d_ws;
  size_t off = 0;
  float* mod  = (float*)(ws + off); off += 40960;
  bf16*  nh   = (bf16*)(ws + off); off += (size_t)SEQ * DIM * 2;
  bf16*  qkvb = (bf16*)(ws + off); off += (size_t)SEQ * QKVW * 2;
  bf16*  catb = (bf16*)(ws + off); off += (size_t)SEQ * CATW * 2;
  bf16*  wqb  = (bf16*)(ws + off); off += (size_t)FUSED * DIM * 2;
  bf16*  wpb  = (bf16*)(ws + off); off += (size_t)DIM * CATW * 2;
  bf16*  pkbf = (bf16*)(ws + off);
  size_t base = off;
  // adaptive split-K for proj GEMM (bf16 partials): 8 -> 2 -> f32 fallback
  int parts = 0;
  if (ws_size >= base + (size_t)8 * SEQ * DIM * 2) parts = 8;
  else if (ws_size >= base + (size_t)2 * SEQ * DIM * 2) parts = 2;
  bool full = (ws_size >= base) && (parts > 0);

  if (full) {
    k_cvt2<<<dim3(4096), dim3(256), 0, stream>>>(
        qkvml_w, wqb, (size_t)FUSED * DIM, proj_w, wpb, (size_t)DIM * CATW);
  }
  k_mod_gemv<<<dim3(QKVW / 4), dim3(256), 0, stream>>>(temb, norm_w, norm_b, mod);
  k_ln_mod<<<dim3(SEQ), dim3(256), 0, stream>>>(hs, mod, nh);

  if (full) {
    k_gemm8<0><<<dim3(8 * (FUSED / 256)), dim3(512), 0, stream>>>(
        nh, wqb, qkvml_b, DIM, FUSED / 256, 1, qkvb, catb, nullptr);
  } else {
    k_gemm2<0><<<dim3(16 * (FUSED / 128)), dim3(256), 0, stream>>>(
        nh, qkvml_w, qkvml_b, DIM, FUSED / 128, qkvb, catb, nullptr, nullptr, nullptr);
  }

  k_rmsrope<<<dim3(SEQ * 2), dim3(256), 0, stream>>>(qkvb, rope_c, rope_s, rms_q_w, rms_k_w);
  k_attn<<<dim3(SEQ / 64 * NH), dim3(256), 0, stream>>>(qkvb, catb);

  if (full) {
    k_gemm8<1><<<dim3(8 * (DIM / 256) * parts), dim3(512), 0, stream>>>(
        catb, wpb, nullptr, CATW, DIM / 256, parts, nullptr, nullptr, pkbf);
    k_red<<<dim3(SEQ * 3), dim3(256), 0, stream>>>(pkbf, proj_b, mod + 2 * DIM, hs, out, parts);
  } else {
    k_gemm2<1><<<dim3(16 * (DIM / 128)), dim3(256), 0, stream>>>(
        catb, proj_w, proj_b, CATW, DIM / 128, nullptr, nullptr, mod + 2 * DIM, hs, out);
  }
}